// Round 9
// baseline (419.826 us; speedup 1.0000x reference)
//
#include <hip/hip_runtime.h>

#define NN 40000
#define EE 300000
#define DIM 256
#define NHD 4
#define CAP 64
#define LOG2E 1.4426950408889634f

typedef __attribute__((ext_vector_type(8))) short bfrag;   // 8 bf16 in 4 VGPRs
typedef __attribute__((ext_vector_type(4))) float fx4;

static __device__ __forceinline__ float bflo(unsigned u) {
  union { unsigned i; float f; } v; v.i = u << 16; return v.f;        // 1 op
}
static __device__ __forceinline__ float bfhi(unsigned u) {
  union { unsigned i; float f; } v; v.i = u & 0xffff0000u; return v.f; // 1 op
}
static __device__ __forceinline__ unsigned short f2bf(float f) {
  union { float f; unsigned i; } v; v.f = f;
  unsigned x = v.i;
  return (unsigned short)((x + 0x7fffu + ((x >> 16) & 1u)) >> 16);  // RNE
}
static __device__ __forceinline__ void gload_lds16(const unsigned short* g, unsigned short* l) {
  __builtin_amdgcn_global_load_lds((const __attribute__((address_space(1))) void*)g,
                                   (__attribute__((address_space(3))) void*)l, 16, 0, 0);
}

// XCD-locality mapping (R7-proven): within each group of 8*NC blocks, rb_local = idx%8
// (constant per XCD under round-robin dispatch), cb = idx/8 => all NC col-panels of a
// row-block run consecutively on ONE XCD; its X-tile L2-hits after first touch.
static __device__ __forceinline__ void map_rc(int L, int NC, int NR, int& rb, int& cb) {
  int per = 8 * NC;
  int g = L / per;
  int base = g * 8;
  int rig = NR - base; if (rig > 8) rig = 8;
  int idx = L - g * per;
  rb = base + idx % rig;
  cb = idx / rig;
}

// ---------------- shared GEMM core: 128x128 tile, BK=64, single 32KB LDS buffer ------
// 4 waves of 64x64 (acc[4][4]): LDS traffic 24KB/Kout vs 36 at 64x128 (R8 analysis:
// GEMMs are LDS-port-bound). 5 blocks/CU (LDS), ~20 waves/CU; steady-state grids
// (>12 blocks/CU) keep the CU fed. Same R4-proven swizzle: LDS(r,c) holds global
// (r, c^(r&7)); linear LDS dest + pre-swizzled global source (rule #21).
static __device__ __forceinline__ void gemm_core128(const unsigned short* __restrict__ X,
                                                    const unsigned short* __restrict__ WT,
                                                    int R0, int C0,
                                                    fx4 acc[4][4],
                                                    unsigned short* ldsA,   // 8192 shorts
                                                    unsigned short* ldsB) { // 8192 shorts
  const int tid = threadIdx.x;
  const int wave = tid >> 6, lane = tid & 63;
  const int li = lane & 15, lk = lane >> 4;
  const int wr = wave >> 1, wc = wave & 1;
  const int lr = lane >> 3;              // row-within-8 this lane stages
  const int swz = ((lane & 7) ^ lr) * 8; // pre-swizzled source chunk (elems)
#pragma unroll
  for (int kt = 0; kt < 4; ++kt) {
    const int k0 = kt * 64;
    if (kt) __syncthreads();             // prior ds_reads done before overwrite
#pragma unroll
    for (int i = 0; i < 8; ++i) {        // 32 stripes: 16 A (128 rows) + 16 B (128 cols)
      int g = wave * 8 + i;
      if (g < 16) {
        int ra = min(R0 + g * 8 + lr, NN - 1);
        gload_lds16(X + (size_t)ra * DIM + k0 + swz, ldsA + g * 512);
      } else {
        gload_lds16(WT + (size_t)(C0 + (g - 16) * 8 + lr) * DIM + k0 + swz, ldsB + (g - 16) * 512);
      }
    }
    __syncthreads();                     // staging complete (vmcnt drained)
#pragma unroll
    for (int ks = 0; ks < 2; ++ks) {
      bfrag a[4], b[4];
      const int chb = (lk + ks * 4) ^ (li & 7);   // swizzled 16B chunk
#pragma unroll
      for (int mt = 0; mt < 4; ++mt)
        a[mt] = *(const bfrag*)(ldsA + (wr * 64 + mt * 16 + li) * 64 + chb * 8);
#pragma unroll
      for (int nt = 0; nt < 4; ++nt)
        b[nt] = *(const bfrag*)(ldsB + (wc * 64 + nt * 16 + li) * 64 + chb * 8);
#pragma unroll
      for (int mt = 0; mt < 4; ++mt)
#pragma unroll
        for (int nt = 0; nt < 4; ++nt)
          acc[mt][nt] = __builtin_amdgcn_mfma_f32_16x16x32_bf16(a[mt], b[nt], acc[mt][nt], 0, 0, 0);
    }
  }
}

// ---------------- phase 0: f32 -> bf16 conversion of node features ----------------
__global__ __launch_bounds__(256) void cvt_kernel(const float* __restrict__ hA,
                                                  const float* __restrict__ hB,
                                                  unsigned short* __restrict__ XA,
                                                  unsigned short* __restrict__ XB) {
  long id = (long)blockIdx.x * 256 + threadIdx.x;   // one thread = 8 floats
  const long half = (long)NN * DIM / 8;             // 1,280,000
  const float4* src; unsigned short* dst; long o;
  if (id < half) { src = (const float4*)hA; dst = XA; o = id; }
  else           { src = (const float4*)hB; dst = XB; o = id - half; }
  float4 a = src[o * 2], b = src[o * 2 + 1];
  uint4 pk;
  pk.x = (unsigned)f2bf(a.x) | ((unsigned)f2bf(a.y) << 16);
  pk.y = (unsigned)f2bf(a.z) | ((unsigned)f2bf(a.w) << 16);
  pk.z = (unsigned)f2bf(b.x) | ((unsigned)f2bf(b.y) << 16);
  pk.w = (unsigned)f2bf(b.z) | ((unsigned)f2bf(b.w) << 16);
  ((uint4*)dst)[o] = pk;
}

// ---------------- phase 0+1 merged: effective weights + edge bucketing --------------
// blocks [0,2568): weight prep (kv column-interleaved, k pre-scaled rel_pri/8*LOG2E).
// blocks [2568,6084): bucket_build for the 3 relations.
__global__ __launch_bounds__(256) void prep_all(
    const float* __restrict__ Wk, const float* __restrict__ bk,
    const float* __restrict__ Wq, const float* __restrict__ bq,
    const float* __restrict__ Wv, const float* __restrict__ bv,
    const float* __restrict__ Wa,
    const float* __restrict__ rel_att, const float* __restrict__ rel_msg,
    const float* __restrict__ rel_pri,
    unsigned short* __restrict__ WT_A, unsigned short* __restrict__ WT_B,
    unsigned short* __restrict__ WaT, float* __restrict__ biasA, float* __restrict__ biasB,
    const int* __restrict__ src0, const int* __restrict__ dst0,
    const int* __restrict__ src1, const int* __restrict__ dst1,
    const int* __restrict__ src2, const int* __restrict__ dst2,
    int* __restrict__ cnt, int* __restrict__ bkt) {
  if (blockIdx.x >= 2568) {   // ---- bucket build ----
    int bb = blockIdx.x - 2568;
    int r = bb / 1172;
    int e = (bb % 1172) * 256 + threadIdx.x;
    if (e >= EE) return;
    const int* src = r == 0 ? src0 : (r == 1 ? src1 : src2);
    const int* dst = r == 0 ? dst0 : (r == 1 ? dst1 : dst2);
    int d = dst[e];
    int pos = atomicAdd(&cnt[r * NN + d], 1);
    if (pos < CAP) bkt[(size_t)r * NN * CAP + d * CAP + pos] = src[e];
    return;
  }
  int id = blockIdx.x * 256 + threadIdx.x;
  if (id < 262144) {  // WT_A kv cols c in [0,1024)
    int c = id >> 8, i = id & 255;
    int br = c >> 9, w = c & 511, h = w >> 7, ww = w & 127;
    int iskv = (ww >> 2) & 1;
    int j = (ww >> 3) * 4 + (ww & 3);
    int r = br ? 2 : 0;
    const float* W  = iskv ? Wv : Wk;
    const float* RM = iskv ? rel_msg : rel_att;
    const float* wrow = W + i * 256 + h * 64;              // type 0
    const float* rm = RM + (size_t)((r * NHD + h) * 64) * 64 + j;
    float s = 0.f;
#pragma unroll 8
    for (int l = 0; l < 64; l++) s += wrow[l] * rm[l * 64];
    if (!iskv) s *= rel_pri[r * NHD + h] * 0.125f * LOG2E;
    WT_A[c * 256 + i] = f2bf(s);
    return;
  }
  id -= 262144;
  if (id < 65536) {   // qA slab (cols 1024..1279)
    int c = id >> 8, i = id & 255;
    WT_A[(1024 + c) * 256 + i] = f2bf(Wq[i * 256 + c]);    // type 0
    return;
  }
  id -= 65536;
  if (id < 131072) {  // WT_B kv cols c in [0,512), rel 1, type B
    int c = id >> 8, i = id & 255;
    int h = c >> 7, ww = c & 127;
    int iskv = (ww >> 2) & 1;
    int j = (ww >> 3) * 4 + (ww & 3);
    const float* W  = iskv ? Wv : Wk;
    const float* RM = iskv ? rel_msg : rel_att;
    const float* wrow = W + 65536 + i * 256 + h * 64;      // type 1
    const float* rm = RM + (size_t)((1 * NHD + h) * 64) * 64 + j;
    float s = 0.f;
#pragma unroll 8
    for (int l = 0; l < 64; l++) s += wrow[l] * rm[l * 64];
    if (!iskv) s *= rel_pri[1 * NHD + h] * 0.125f * LOG2E;
    WT_B[c * 256 + i] = f2bf(s);
    return;
  }
  id -= 131072;
  if (id < 65536) {   // qB slab (cols 512..767)
    int c = id >> 8, i = id & 255;
    WT_B[(512 + c) * 256 + i] = f2bf(Wq[65536 + i * 256 + c]);  // type 1
    return;
  }
  id -= 65536;
  if (id < 131072) {  // WaT transpose
    int t = id >> 16, rem = id & 65535, c = rem >> 8, i = rem & 255;
    WaT[t * 65536 + c * 256 + i] = f2bf(Wa[t * 65536 + i * 256 + c]);
    return;
  }
  id -= 131072;
  if (id < 2048) {    // biases
    if (id < 1280) {
      int c = id; float s;
      if (c < 1024) {
        int br = c >> 9, w = c & 511, h = w >> 7, ww = w & 127;
        int iskv = (ww >> 2) & 1;
        int j = (ww >> 3) * 4 + (ww & 3);
        int r = br ? 2 : 0;
        const float* B  = iskv ? bv : bk;
        const float* RM = iskv ? rel_msg : rel_att;
        s = 0.f;
        for (int l = 0; l < 64; l++)
          s += B[h * 64 + l] * RM[(size_t)((r * NHD + h) * 64 + l) * 64 + j];
        if (!iskv) s *= rel_pri[r * NHD + h] * 0.125f * LOG2E;
      } else s = bq[c - 1024];
      biasA[c] = s;
    } else {
      int c = id - 1280; float s;
      if (c < 512) {
        int h = c >> 7, ww = c & 127;
        int iskv = (ww >> 2) & 1;
        int j = (ww >> 3) * 4 + (ww & 3);
        const float* B  = iskv ? bv : bk;
        const float* RM = iskv ? rel_msg : rel_att;
        s = 0.f;
        for (int l = 0; l < 64; l++)
          s += B[256 + h * 64 + l] * RM[(size_t)((1 * NHD + h) * 64 + l) * 64 + j];
        if (!iskv) s *= rel_pri[1 * NHD + h] * 0.125f * LOG2E;
      } else s = bq[256 + (c - 512)];
      biasB[c] = s;
    }
  }
}

// ---------------- phase 2: fused KVQ GEMM (128x128 core, XCD-local mapping) ---------
__global__ __launch_bounds__(256) void gemm_kvq(const unsigned short* __restrict__ X,
                                                const unsigned short* __restrict__ WT,
                                                const float* __restrict__ bias,
                                                unsigned short* __restrict__ Out,
                                                int ldOut, int NC) {
  __shared__ unsigned short ldsA[8192], ldsB[8192];
  fx4 acc[4][4] = {};
  int rb, cb; map_rc(blockIdx.x, NC, 313, rb, cb);
  const int R0 = rb * 128, C0 = cb * 128;
  gemm_core128(X, WT, R0, C0, acc, ldsA, ldsB);
  const int wave = threadIdx.x >> 6, lane = threadIdx.x & 63;
  const int li = lane & 15, lk = lane >> 4;
  const int wr = wave >> 1, wc = wave & 1;
#pragma unroll
  for (int mt = 0; mt < 4; mt++)
#pragma unroll
    for (int nt = 0; nt < 4; nt++) {
      int col = C0 + wc * 64 + nt * 16 + li;
      float bcol = bias[col];
      int rbase = R0 + wr * 64 + mt * 16 + lk * 4;
#pragma unroll
      for (int i = 0; i < 4; i++) {
        int row = rbase + i;
        if (row < NN) Out[(long)row * ldOut + col] = f2bf(acc[mt][nt][i] + bcol);
      }
    }
}

// ---------------- phase 3: per-destination aggregation (exp2 softmax) ----------------
template<int LD>
static __device__ __forceinline__ void proc_bucket(const unsigned short* __restrict__ Out,
                                                   int c, int srcs, int kvoff,
                                                   float q0, float q1, float q2, float q3,
                                                   float& L, float& A0, float& A1, float& A2, float& A3) {
  const uint4 Z = {0u, 0u, 0u, 0u};
  auto ldx = [&](int E) -> uint4 {
    int s = __builtin_amdgcn_readlane(srcs, E & 63);
    return *(const uint4*)(Out + (size_t)s * LD + kvoff);
  };
  auto proc = [&](uint4 u) {
    float pp = q0 * bflo(u.x) + q1 * bfhi(u.x) + q2 * bflo(u.y) + q3 * bfhi(u.y);
    pp += __shfl_xor(pp, 1); pp += __shfl_xor(pp, 2);
    pp += __shfl_xor(pp, 4); pp += __shfl_xor(pp, 8);
    float p = exp2f(pp);                 // v_exp_f32 native (log2e pre-folded into k)
    L += p;
    A0 += p * bflo(u.z); A1 += p * bfhi(u.z);
    A2 += p * bflo(u.w); A3 += p * bfhi(u.w);
  };
  uint4 e0 = Z, e1 = Z, e2 = Z, e3 = Z;
  if (0 < c) e0 = ldx(0);
  if (1 < c) e1 = ldx(1);
  if (2 < c) e2 = ldx(2);
  if (3 < c) e3 = ldx(3);
  for (int e = 0; e < c; e += 4) {
    uint4 f0 = Z, f1 = Z, f2 = Z, f3 = Z;
    if (e + 4 < c) f0 = ldx(e + 4);
    if (e + 5 < c) f1 = ldx(e + 5);
    if (e + 6 < c) f2 = ldx(e + 6);
    if (e + 7 < c) f3 = ldx(e + 7);
    proc(e0);
    if (e + 1 < c) proc(e1);
    if (e + 2 < c) proc(e2);
    if (e + 3 < c) proc(e3);
    e0 = f0; e1 = f1; e2 = f2; e3 = f3;
  }
}

__global__ __launch_bounds__(256) void agg_all(const unsigned short* __restrict__ OutA,
                                               const unsigned short* __restrict__ OutB,
                                               const int* __restrict__ cnt,
                                               const int* __restrict__ bkt,
                                               unsigned short* __restrict__ tA,
                                               unsigned short* __restrict__ tB) {
  int wid = (blockIdx.x * 256 + threadIdx.x) >> 6;
  int lane = threadIdx.x & 63;
  int h = lane >> 4, li = lane & 15;
  int qoff = h * 64 + li * 4;          // q / output element offset
  int kvoff = h * 128 + li * 8;        // interleaved kv offset (uint4 per lane)
  if (wid < NN) {
    int n = wid;
    uint2 qr = *(const uint2*)(OutB + (size_t)n * 768 + 512 + qoff);
    float q0 = bflo(qr.x), q1 = bfhi(qr.x), q2 = bflo(qr.y), q3 = bfhi(qr.y);
    int c0 = min(cnt[n], CAP);
    int c2 = min(cnt[2 * NN + n], CAP);
    int s0 = (lane < c0) ? bkt[(size_t)n * CAP + lane] : 0;
    int s2 = (lane < c2) ? bkt[(size_t)2 * NN * CAP + n * CAP + lane] : 0;
    float l0 = 0.f, b00 = 0.f, b01 = 0.f, b02 = 0.f, b03 = 0.f;
    float l2 = 0.f, b20 = 0.f, b21 = 0.f, b22 = 0.f, b23 = 0.f;
    proc_bucket<1280>(OutA,       c0, s0, kvoff, q0, q1, q2, q3, l0, b00, b01, b02, b03);
    proc_bucket<1280>(OutA + 512, c2, s2, kvoff, q0, q1, q2, q3, l2, b20, b21, b22, b23);
    float i0 = (l0 > 0.f) ? 0.5f / l0 : 0.f;
    float i2 = (l2 > 0.f) ? 0.5f / l2 : 0.f;
    float r0 = b00 * i0 + b20 * i2, r1 = b01 * i0 + b21 * i2;
    float r2 = b02 * i0 + b22 * i2, r3 = b03 * i0 + b23 * i2;
    uint2 pk;
    pk.x = (unsigned)f2bf(r0) | ((unsigned)f2bf(r1) << 16);
    pk.y = (unsigned)f2bf(r2) | ((unsigned)f2bf(r3) << 16);
    *(uint2*)(tB + (size_t)n * DIM + qoff) = pk;
  } else if (wid < 2 * NN) {
    int n = wid - NN;
    uint2 qr = *(const uint2*)(OutA + (size_t)n * 1280 + 1024 + qoff);
    float q0 = bflo(qr.x), q1 = bfhi(qr.x), q2 = bflo(qr.y), q3 = bfhi(qr.y);
    int c = min(cnt[NN + n], CAP);
    int s1 = (lane < c) ? bkt[(size_t)NN * CAP + n * CAP + lane] : 0;
    float l = 0.f, a0 = 0.f, a1 = 0.f, a2 = 0.f, a3 = 0.f;
    proc_bucket<768>(OutB, c, s1, kvoff, q0, q1, q2, q3, l, a0, a1, a2, a3);
    float inv = (l > 0.f) ? 1.f / l : 0.f;
    uint2 pk;
    pk.x = (unsigned)f2bf(a0 * inv) | ((unsigned)f2bf(a1 * inv) << 16);
    pk.y = (unsigned)f2bf(a2 * inv) | ((unsigned)f2bf(a3 * inv) << 16);
    *(uint2*)(tA + (size_t)n * DIM + qoff) = pk;
  }
}

// ---------------- phase 4: output GEMM + sigmoid-skip residual (both types) ----------
__global__ __launch_bounds__(256) void gemm_final2(const unsigned short* __restrict__ tA,
                                                   const unsigned short* __restrict__ tB,
                                                   const unsigned short* __restrict__ XA,
                                                   const unsigned short* __restrict__ XB,
                                                   const unsigned short* __restrict__ WaT,
                                                   const float* __restrict__ ba,
                                                   const float* __restrict__ skip,
                                                   float* __restrict__ outp) {
  __shared__ unsigned short ldsA[8192], ldsB[8192];
  const int t = blockIdx.y;
  const unsigned short* Tt = t ? tB : tA;
  const unsigned short* hin = t ? XB : XA;   // bf16 residual
  float* op = outp + (size_t)t * NN * DIM;
  fx4 acc[4][4] = {};
  int rb, cb; map_rc(blockIdx.x, 2, 313, rb, cb);
  const int R0 = rb * 128, C0 = cb * 128;
  gemm_core128(Tt, WaT + t * 65536, R0, C0, acc, ldsA, ldsB);
  const int wave = threadIdx.x >> 6, lane = threadIdx.x & 63;
  const int li = lane & 15, lk = lane >> 4;
  const int wr = wave >> 1, wc = wave & 1;
  float alpha = 1.f / (1.f + __expf(-skip[t]));
  float beta = 1.f - alpha;
#pragma unroll
  for (int mt = 0; mt < 4; mt++)
#pragma unroll
    for (int nt = 0; nt < 4; nt++) {
      int col = C0 + wc * 64 + nt * 16 + li;
      float bcol = ba[t * 256 + col];
      int rbase = R0 + wr * 64 + mt * 16 + lk * 4;
#pragma unroll
      for (int i = 0; i < 4; i++) {
        int row = rbase + i;
        if (row < NN) {
          float hv = bflo((unsigned)hin[(size_t)row * DIM + col]);
          op[(long)row * DIM + col] = (acc[mt][nt][i] + bcol) * alpha + hv * beta;
        }
      }
    }
}

extern "C" void kernel_launch(void* const* d_in, const int* in_sizes, int n_in,
                              void* d_out, int out_size, void* d_ws, size_t ws_size,
                              hipStream_t stream) {
  const float* hA = (const float*)d_in[0];
  const float* hB = (const float*)d_in[1];
  const int* src0 = (const int*)d_in[2];
  const int* dst0 = (const int*)d_in[3];
  const int* src1 = (const int*)d_in[4];
  const int* dst1 = (const int*)d_in[5];
  const int* src2 = (const int*)d_in[6];
  const int* dst2 = (const int*)d_in[7];
  const float* Wk = (const float*)d_in[8];
  const float* bk = (const float*)d_in[9];
  const float* Wq = (const float*)d_in[10];
  const float* bq = (const float*)d_in[11];
  const float* Wv = (const float*)d_in[12];
  const float* bv = (const float*)d_in[13];
  const float* Wa = (const float*)d_in[14];
  const float* ba = (const float*)d_in[15];
  const float* rel_att = (const float*)d_in[16];
  const float* rel_msg = (const float*)d_in[17];
  const float* rel_pri = (const float*)d_in[18];
  const float* skip = (const float*)d_in[19];

  char* w = (char*)d_ws;
  unsigned short* XA   = (unsigned short*)(w);                 // 20,480,000 B
  unsigned short* XB   = (unsigned short*)(w + 20480000);      // 20,480,000 B
  unsigned short* OutA = (unsigned short*)(w + 40960000);      // 102,400,000 B
  unsigned short* OutB = (unsigned short*)(w + 143360000);     // 61,440,000 B
  unsigned short* WT_A = (unsigned short*)(w + 204800000);     // 655,360 B
  unsigned short* WT_B = (unsigned short*)(w + 205455360);     // 393,216 B
  unsigned short* WaT  = (unsigned short*)(w + 205848576);     // 262,144 B
  float* biasA = (float*)(w + 206110720);                      // 5,120 B
  float* biasB = (float*)(w + 206115840);                      // 3,072 B
  int* cnt  = (int*)(w + 206118912);                           // 3 x 160,000 B
  int* bkt  = (int*)(w + 206598912);                           // 3 x 10,240,000 B
  unsigned short* tA = (unsigned short*)(w + 237318912);       // 20,480,000 B
  unsigned short* tB = (unsigned short*)(w + 257798912);       // 20,480,000 B

  hipMemsetAsync(cnt, 0, 3 * NN * sizeof(int), stream);
  cvt_kernel<<<10000, 256, 0, stream>>>(hA, hB, XA, XB);
  prep_all<<<6084, 256, 0, stream>>>(Wk, bk, Wq, bq, Wv, bv, Wa,
                                     rel_att, rel_msg, rel_pri,
                                     WT_A, WT_B, WaT, biasA, biasB,
                                     src0, dst0, src1, dst1, src2, dst2, cnt, bkt);
  gemm_kvq<<<3130, 256, 0, stream>>>(XA, WT_A, biasA, OutA, 1280, 10);
  gemm_kvq<<<1878, 256, 0, stream>>>(XB, WT_B, biasB, OutB, 768, 6);
  agg_all<<<20000, 256, 0, stream>>>(OutA, OutB, cnt, bkt, tA, tB);
  gemm_final2<<<dim3(626, 2), 256, 0, stream>>>(tA, tB, XA, XB, WaT, ba, skip, (float*)d_out);
}

// Round 10
// 352.856 us; speedup vs baseline: 1.1898x; 1.1898x over previous
//
#include <hip/hip_runtime.h>

#define NN 40000
#define EE 300000
#define DIM 256
#define NHD 4
#define CAP 64
#define LOG2E 1.4426950408889634f

typedef __attribute__((ext_vector_type(8))) short bfrag;   // 8 bf16 in 4 VGPRs
typedef __attribute__((ext_vector_type(4))) float fx4;

static __device__ __forceinline__ float bflo(unsigned u) {
  union { unsigned i; float f; } v; v.i = u << 16; return v.f;        // 1 op
}
static __device__ __forceinline__ float bfhi(unsigned u) {
  union { unsigned i; float f; } v; v.i = u & 0xffff0000u; return v.f; // 1 op
}
static __device__ __forceinline__ unsigned short f2bf(float f) {
  union { float f; unsigned i; } v; v.f = f;
  unsigned x = v.i;
  return (unsigned short)((x + 0x7fffu + ((x >> 16) & 1u)) >> 16);  // RNE
}
static __device__ __forceinline__ void gload_lds16(const unsigned short* g, unsigned short* l) {
  __builtin_amdgcn_global_load_lds((const __attribute__((address_space(1))) void*)g,
                                   (__attribute__((address_space(3))) void*)l, 16, 0, 0);
}

// XCD-locality mapping (R7-proven): within each group of 8*NC blocks, rb_local = idx%8
// (constant per XCD under round-robin dispatch), cb = idx/8 => all NC col-panels of a
// row-block run consecutively on ONE XCD; its X-tile L2-hits after first touch.
static __device__ __forceinline__ void map_rc(int L, int NC, int NR, int& rb, int& cb) {
  int per = 8 * NC;
  int g = L / per;
  int base = g * 8;
  int rig = NR - base; if (rig > 8) rig = 8;
  int idx = L - g * per;
  rb = base + idx % rig;
  cb = idx / rig;
}

// ---------------- shared GEMM core: 64x128 tile, BK=64, single 24KB LDS buffer ------
// (R4/R7-proven; R5/R8/R9 alternatives all regressed - do not restructure.)
// 6 blocks/CU => ~24 waves/CU; TLP hides stage latency (m114).
// 16B-chunk swizzle: LDS(r,c) holds global(r, c^(r&7)); linear LDS dest + pre-swizzled
// global source (rule #21), swizzled ds_read. Rows exact (625*64=40000): no guards.
static __device__ __forceinline__ void gemm_core64(const unsigned short* __restrict__ X,
                                                   const unsigned short* __restrict__ WT,
                                                   int R0, int C0,
                                                   fx4 acc[2][4],
                                                   unsigned short* ldsA,   // 4096 shorts
                                                   unsigned short* ldsB) { // 8192 shorts
  const int tid = threadIdx.x;
  const int wave = tid >> 6, lane = tid & 63;
  const int li = lane & 15, lk = lane >> 4;
  const int wr = wave >> 1, wc = wave & 1;
  const int lr = lane >> 3;              // row-within-8 this lane stages
  const int swz = ((lane & 7) ^ lr) * 8; // pre-swizzled source chunk (elems)
#pragma unroll
  for (int kt = 0; kt < 4; ++kt) {
    const int k0 = kt * 64;
    if (kt) __syncthreads();             // prior ds_reads done before overwrite
#pragma unroll
    for (int i = 0; i < 6; ++i) {        // 24 stripes: 8 for A (64 rows), 16 for B (128)
      int g = wave * 6 + i;
      if (g < 8) gload_lds16(X + (size_t)(R0 + g * 8 + lr) * DIM + k0 + swz, ldsA + g * 512);
      else       gload_lds16(WT + (size_t)(C0 + (g - 8) * 8 + lr) * DIM + k0 + swz, ldsB + (g - 8) * 512);
    }
    __syncthreads();                     // staging complete (vmcnt drained)
#pragma unroll
    for (int ks = 0; ks < 2; ++ks) {
      bfrag a[2], b[4];
      const int chb = (lk + ks * 4) ^ (li & 7);   // swizzled 16B chunk
#pragma unroll
      for (int mt = 0; mt < 2; ++mt)
        a[mt] = *(const bfrag*)(ldsA + (wr * 32 + mt * 16 + li) * 64 + chb * 8);
#pragma unroll
      for (int nt = 0; nt < 4; ++nt)
        b[nt] = *(const bfrag*)(ldsB + (wc * 64 + nt * 16 + li) * 64 + chb * 8);
#pragma unroll
      for (int mt = 0; mt < 2; ++mt)
#pragma unroll
        for (int nt = 0; nt < 4; ++nt)
          acc[mt][nt] = __builtin_amdgcn_mfma_f32_16x16x32_bf16(a[mt], b[nt], acc[mt][nt], 0, 0, 0);
    }
  }
}

// ---------------- phase 0+1 merged: cvt + effective weights + edge bucketing --------
// blocks [0,2568): weight prep (kv column-interleaved, k pre-scaled rel_pri/8*LOG2E).
// blocks [2568,6084): bucket_build for the 3 relations.
// blocks [6084,16084): f32 -> bf16 conversion of node features (old cvt_kernel).
// All three are mutually independent => run concurrently in one dispatch.
__global__ __launch_bounds__(256) void prep_all(
    const float* __restrict__ hA, const float* __restrict__ hB,
    unsigned short* __restrict__ XA, unsigned short* __restrict__ XB,
    const float* __restrict__ Wk, const float* __restrict__ bk,
    const float* __restrict__ Wq, const float* __restrict__ bq,
    const float* __restrict__ Wv, const float* __restrict__ bv,
    const float* __restrict__ Wa,
    const float* __restrict__ rel_att, const float* __restrict__ rel_msg,
    const float* __restrict__ rel_pri,
    unsigned short* __restrict__ WT_A, unsigned short* __restrict__ WT_B,
    unsigned short* __restrict__ WaT, float* __restrict__ biasA, float* __restrict__ biasB,
    const int* __restrict__ src0, const int* __restrict__ dst0,
    const int* __restrict__ src1, const int* __restrict__ dst1,
    const int* __restrict__ src2, const int* __restrict__ dst2,
    int* __restrict__ cnt, int* __restrict__ bkt) {
  if (blockIdx.x >= 6084) {   // ---- cvt: f32 -> bf16 node features ----
    long id = (long)(blockIdx.x - 6084) * 256 + threadIdx.x;   // one thread = 8 floats
    const long half = (long)NN * DIM / 8;                      // 1,280,000
    const float4* src; unsigned short* dst; long o;
    if (id < half) { src = (const float4*)hA; dst = XA; o = id; }
    else           { src = (const float4*)hB; dst = XB; o = id - half; }
    float4 a = src[o * 2], b = src[o * 2 + 1];
    uint4 pk;
    pk.x = (unsigned)f2bf(a.x) | ((unsigned)f2bf(a.y) << 16);
    pk.y = (unsigned)f2bf(a.z) | ((unsigned)f2bf(a.w) << 16);
    pk.z = (unsigned)f2bf(b.x) | ((unsigned)f2bf(b.y) << 16);
    pk.w = (unsigned)f2bf(b.z) | ((unsigned)f2bf(b.w) << 16);
    ((uint4*)dst)[o] = pk;
    return;
  }
  if (blockIdx.x >= 2568) {   // ---- bucket build ----
    int bb = blockIdx.x - 2568;
    int r = bb / 1172;
    int e = (bb % 1172) * 256 + threadIdx.x;
    if (e >= EE) return;
    const int* src = r == 0 ? src0 : (r == 1 ? src1 : src2);
    const int* dst = r == 0 ? dst0 : (r == 1 ? dst1 : dst2);
    int d = dst[e];
    int pos = atomicAdd(&cnt[r * NN + d], 1);
    if (pos < CAP) bkt[(size_t)r * NN * CAP + d * CAP + pos] = src[e];
    return;
  }
  int id = blockIdx.x * 256 + threadIdx.x;
  if (id < 262144) {  // WT_A kv cols c in [0,1024)
    int c = id >> 8, i = id & 255;
    int br = c >> 9, w = c & 511, h = w >> 7, ww = w & 127;
    int iskv = (ww >> 2) & 1;
    int j = (ww >> 3) * 4 + (ww & 3);
    int r = br ? 2 : 0;
    const float* W  = iskv ? Wv : Wk;
    const float* RM = iskv ? rel_msg : rel_att;
    const float* wrow = W + i * 256 + h * 64;              // type 0
    const float* rm = RM + (size_t)((r * NHD + h) * 64) * 64 + j;
    float s = 0.f;
#pragma unroll 8
    for (int l = 0; l < 64; l++) s += wrow[l] * rm[l * 64];
    if (!iskv) s *= rel_pri[r * NHD + h] * 0.125f * LOG2E;
    WT_A[c * 256 + i] = f2bf(s);
    return;
  }
  id -= 262144;
  if (id < 65536) {   // qA slab (cols 1024..1279)
    int c = id >> 8, i = id & 255;
    WT_A[(1024 + c) * 256 + i] = f2bf(Wq[i * 256 + c]);    // type 0
    return;
  }
  id -= 65536;
  if (id < 131072) {  // WT_B kv cols c in [0,512), rel 1, type B
    int c = id >> 8, i = id & 255;
    int h = c >> 7, ww = c & 127;
    int iskv = (ww >> 2) & 1;
    int j = (ww >> 3) * 4 + (ww & 3);
    const float* W  = iskv ? Wv : Wk;
    const float* RM = iskv ? rel_msg : rel_att;
    const float* wrow = W + 65536 + i * 256 + h * 64;      // type 1
    const float* rm = RM + (size_t)((1 * NHD + h) * 64) * 64 + j;
    float s = 0.f;
#pragma unroll 8
    for (int l = 0; l < 64; l++) s += wrow[l] * rm[l * 64];
    if (!iskv) s *= rel_pri[1 * NHD + h] * 0.125f * LOG2E;
    WT_B[c * 256 + i] = f2bf(s);
    return;
  }
  id -= 131072;
  if (id < 65536) {   // qB slab (cols 512..767)
    int c = id >> 8, i = id & 255;
    WT_B[(512 + c) * 256 + i] = f2bf(Wq[65536 + i * 256 + c]);  // type 1
    return;
  }
  id -= 65536;
  if (id < 131072) {  // WaT transpose
    int t = id >> 16, rem = id & 65535, c = rem >> 8, i = rem & 255;
    WaT[t * 65536 + c * 256 + i] = f2bf(Wa[t * 65536 + i * 256 + c]);
    return;
  }
  id -= 131072;
  if (id < 2048) {    // biases
    if (id < 1280) {
      int c = id; float s;
      if (c < 1024) {
        int br = c >> 9, w = c & 511, h = w >> 7, ww = w & 127;
        int iskv = (ww >> 2) & 1;
        int j = (ww >> 3) * 4 + (ww & 3);
        int r = br ? 2 : 0;
        const float* B  = iskv ? bv : bk;
        const float* RM = iskv ? rel_msg : rel_att;
        s = 0.f;
        for (int l = 0; l < 64; l++)
          s += B[h * 64 + l] * RM[(size_t)((r * NHD + h) * 64 + l) * 64 + j];
        if (!iskv) s *= rel_pri[r * NHD + h] * 0.125f * LOG2E;
      } else s = bq[c - 1024];
      biasA[c] = s;
    } else {
      int c = id - 1280; float s;
      if (c < 512) {
        int h = c >> 7, ww = c & 127;
        int iskv = (ww >> 2) & 1;
        int j = (ww >> 3) * 4 + (ww & 3);
        const float* B  = iskv ? bv : bk;
        const float* RM = iskv ? rel_msg : rel_att;
        s = 0.f;
        for (int l = 0; l < 64; l++)
          s += B[256 + h * 64 + l] * RM[(size_t)((1 * NHD + h) * 64 + l) * 64 + j];
        if (!iskv) s *= rel_pri[1 * NHD + h] * 0.125f * LOG2E;
      } else s = bq[256 + (c - 512)];
      biasB[c] = s;
    }
  }
}

// ---------------- phase 2: fused KVQ GEMM, both node types in ONE dispatch ----------
// blocks [0,6250): type A (NC=10), [6250,10000): type B (NC=6). bf16 core (R7-proven).
// Per-segment map_rc keeps XCD constancy (segment groups stay contiguous mod 8).
__global__ __launch_bounds__(256) void gemm_kvq(const unsigned short* __restrict__ XA,
                                                const unsigned short* __restrict__ XB,
                                                const unsigned short* __restrict__ WT_A,
                                                const unsigned short* __restrict__ WT_B,
                                                const float* __restrict__ biasA,
                                                const float* __restrict__ biasB,
                                                unsigned short* __restrict__ OutA,
                                                unsigned short* __restrict__ OutB) {
  __shared__ unsigned short ldsA[4096], ldsB[8192];
  const unsigned short* X; const unsigned short* WT; const float* bias;
  unsigned short* Out; int ldOut, NC, Lb;
  if (blockIdx.x < 6250) { X = XA; WT = WT_A; bias = biasA; Out = OutA; ldOut = 1280; NC = 10; Lb = blockIdx.x; }
  else                   { X = XB; WT = WT_B; bias = biasB; Out = OutB; ldOut = 768;  NC = 6;  Lb = blockIdx.x - 6250; }
  fx4 acc[2][4] = {};
  int rb, cb; map_rc(Lb, NC, 625, rb, cb);
  const int R0 = rb * 64, C0 = cb * 128;
  gemm_core64(X, WT, R0, C0, acc, ldsA, ldsB);
  const int wave = threadIdx.x >> 6, lane = threadIdx.x & 63;
  const int li = lane & 15, lk = lane >> 4;
  const int wr = wave >> 1, wc = wave & 1;
#pragma unroll
  for (int mt = 0; mt < 2; mt++)
#pragma unroll
    for (int nt = 0; nt < 4; nt++) {
      int col = C0 + wc * 64 + nt * 16 + li;
      float bcol = bias[col];
      int rbase = R0 + wr * 32 + mt * 16 + lk * 4;
#pragma unroll
      for (int i = 0; i < 4; i++)
        Out[(long)(rbase + i) * ldOut + col] = f2bf(acc[mt][nt][i] + bcol);
    }
}

// ---------------- phase 3: per-destination aggregation (exp2 softmax) ----------------
// Structural L2-miss-path BW wall: 920 MB inherent gather @ ~6.8 TB/s = 135 us.
// Verified invariant across 4 implementations (R4-R9). Do not touch.
template<int LD>
static __device__ __forceinline__ void proc_bucket(const unsigned short* __restrict__ Out,
                                                   int c, int srcs, int kvoff,
                                                   float q0, float q1, float q2, float q3,
                                                   float& L, float& A0, float& A1, float& A2, float& A3) {
  const uint4 Z = {0u, 0u, 0u, 0u};
  auto ldx = [&](int E) -> uint4 {
    int s = __builtin_amdgcn_readlane(srcs, E & 63);
    return *(const uint4*)(Out + (size_t)s * LD + kvoff);
  };
  auto proc = [&](uint4 u) {
    float pp = q0 * bflo(u.x) + q1 * bfhi(u.x) + q2 * bflo(u.y) + q3 * bfhi(u.y);
    pp += __shfl_xor(pp, 1); pp += __shfl_xor(pp, 2);
    pp += __shfl_xor(pp, 4); pp += __shfl_xor(pp, 8);
    float p = exp2f(pp);                 // v_exp_f32 native (log2e pre-folded into k)
    L += p;
    A0 += p * bflo(u.z); A1 += p * bfhi(u.z);
    A2 += p * bflo(u.w); A3 += p * bfhi(u.w);
  };
  uint4 e0 = Z, e1 = Z, e2 = Z, e3 = Z;
  if (0 < c) e0 = ldx(0);
  if (1 < c) e1 = ldx(1);
  if (2 < c) e2 = ldx(2);
  if (3 < c) e3 = ldx(3);
  for (int e = 0; e < c; e += 4) {
    uint4 f0 = Z, f1 = Z, f2 = Z, f3 = Z;
    if (e + 4 < c) f0 = ldx(e + 4);
    if (e + 5 < c) f1 = ldx(e + 5);
    if (e + 6 < c) f2 = ldx(e + 6);
    if (e + 7 < c) f3 = ldx(e + 7);
    proc(e0);
    if (e + 1 < c) proc(e1);
    if (e + 2 < c) proc(e2);
    if (e + 3 < c) proc(e3);
    e0 = f0; e1 = f1; e2 = f2; e3 = f3;
  }
}

__global__ __launch_bounds__(256) void agg_all(const unsigned short* __restrict__ OutA,
                                               const unsigned short* __restrict__ OutB,
                                               const int* __restrict__ cnt,
                                               const int* __restrict__ bkt,
                                               unsigned short* __restrict__ tA,
                                               unsigned short* __restrict__ tB) {
  int wid = (blockIdx.x * 256 + threadIdx.x) >> 6;
  int lane = threadIdx.x & 63;
  int h = lane >> 4, li = lane & 15;
  int qoff = h * 64 + li * 4;          // q / output element offset
  int kvoff = h * 128 + li * 8;        // interleaved kv offset (uint4 per lane)
  if (wid < NN) {
    int n = wid;
    uint2 qr = *(const uint2*)(OutB + (size_t)n * 768 + 512 + qoff);
    float q0 = bflo(qr.x), q1 = bfhi(qr.x), q2 = bflo(qr.y), q3 = bfhi(qr.y);
    int c0 = min(cnt[n], CAP);
    int c2 = min(cnt[2 * NN + n], CAP);
    int s0 = (lane < c0) ? bkt[(size_t)n * CAP + lane] : 0;
    int s2 = (lane < c2) ? bkt[(size_t)2 * NN * CAP + n * CAP + lane] : 0;
    float l0 = 0.f, b00 = 0.f, b01 = 0.f, b02 = 0.f, b03 = 0.f;
    float l2 = 0.f, b20 = 0.f, b21 = 0.f, b22 = 0.f, b23 = 0.f;
    proc_bucket<1280>(OutA,       c0, s0, kvoff, q0, q1, q2, q3, l0, b00, b01, b02, b03);
    proc_bucket<1280>(OutA + 512, c2, s2, kvoff, q0, q1, q2, q3, l2, b20, b21, b22, b23);
    float i0 = (l0 > 0.f) ? 0.5f / l0 : 0.f;
    float i2 = (l2 > 0.f) ? 0.5f / l2 : 0.f;
    float r0 = b00 * i0 + b20 * i2, r1 = b01 * i0 + b21 * i2;
    float r2 = b02 * i0 + b22 * i2, r3 = b03 * i0 + b23 * i2;
    uint2 pk;
    pk.x = (unsigned)f2bf(r0) | ((unsigned)f2bf(r1) << 16);
    pk.y = (unsigned)f2bf(r2) | ((unsigned)f2bf(r3) << 16);
    *(uint2*)(tB + (size_t)n * DIM + qoff) = pk;
  } else if (wid < 2 * NN) {
    int n = wid - NN;
    uint2 qr = *(const uint2*)(OutA + (size_t)n * 1280 + 1024 + qoff);
    float q0 = bflo(qr.x), q1 = bfhi(qr.x), q2 = bflo(qr.y), q3 = bfhi(qr.y);
    int c = min(cnt[NN + n], CAP);
    int s1 = (lane < c) ? bkt[(size_t)NN * CAP + n * CAP + lane] : 0;
    float l = 0.f, a0 = 0.f, a1 = 0.f, a2 = 0.f, a3 = 0.f;
    proc_bucket<768>(OutB, c, s1, kvoff, q0, q1, q2, q3, l, a0, a1, a2, a3);
    float inv = (l > 0.f) ? 1.f / l : 0.f;
    uint2 pk;
    pk.x = (unsigned)f2bf(a0 * inv) | ((unsigned)f2bf(a1 * inv) << 16);
    pk.y = (unsigned)f2bf(a2 * inv) | ((unsigned)f2bf(a3 * inv) << 16);
    *(uint2*)(tA + (size_t)n * DIM + qoff) = pk;
  }
}

// ---------------- phase 4: output GEMM + sigmoid-skip residual (both types) ----------
__global__ __launch_bounds__(256) void gemm_final2(const unsigned short* __restrict__ tA,
                                                   const unsigned short* __restrict__ tB,
                                                   const unsigned short* __restrict__ XA,
                                                   const unsigned short* __restrict__ XB,
                                                   const unsigned short* __restrict__ WaT,
                                                   const float* __restrict__ ba,
                                                   const float* __restrict__ skip,
                                                   float* __restrict__ outp) {
  __shared__ unsigned short ldsA[4096], ldsB[8192];
  const int t = blockIdx.y;
  const unsigned short* Tt = t ? tB : tA;
  const unsigned short* hin = t ? XB : XA;   // bf16 residual
  float* op = outp + (size_t)t * NN * DIM;
  fx4 acc[2][4] = {};
  int rb, cb; map_rc(blockIdx.x, 2, 625, rb, cb);
  const int R0 = rb * 64, C0 = cb * 128;
  gemm_core64(Tt, WaT + t * 65536, R0, C0, acc, ldsA, ldsB);
  const int wave = threadIdx.x >> 6, lane = threadIdx.x & 63;
  const int li = lane & 15, lk = lane >> 4;
  const int wr = wave >> 1, wc = wave & 1;
  float alpha = 1.f / (1.f + __expf(-skip[t]));
  float beta = 1.f - alpha;
#pragma unroll
  for (int mt = 0; mt < 2; mt++)
#pragma unroll
    for (int nt = 0; nt < 4; nt++) {
      int col = C0 + wc * 64 + nt * 16 + li;
      float bcol = ba[t * 256 + col];
      int rbase = R0 + wr * 32 + mt * 16 + lk * 4;
#pragma unroll
      for (int i = 0; i < 4; i++) {
        int row = rbase + i;
        float hv = bflo((unsigned)hin[(size_t)row * DIM + col]);
        op[(long)row * DIM + col] = (acc[mt][nt][i] + bcol) * alpha + hv * beta;
      }
    }
}

extern "C" void kernel_launch(void* const* d_in, const int* in_sizes, int n_in,
                              void* d_out, int out_size, void* d_ws, size_t ws_size,
                              hipStream_t stream) {
  const float* hA = (const float*)d_in[0];
  const float* hB = (const float*)d_in[1];
  const int* src0 = (const int*)d_in[2];
  const int* dst0 = (const int*)d_in[3];
  const int* src1 = (const int*)d_in[4];
  const int* dst1 = (const int*)d_in[5];
  const int* src2 = (const int*)d_in[6];
  const int* dst2 = (const int*)d_in[7];
  const float* Wk = (const float*)d_in[8];
  const float* bk = (const float*)d_in[9];
  const float* Wq = (const float*)d_in[10];
  const float* bq = (const float*)d_in[11];
  const float* Wv = (const float*)d_in[12];
  const float* bv = (const float*)d_in[13];
  const float* Wa = (const float*)d_in[14];
  const float* ba = (const float*)d_in[15];
  const float* rel_att = (const float*)d_in[16];
  const float* rel_msg = (const float*)d_in[17];
  const float* rel_pri = (const float*)d_in[18];
  const float* skip = (const float*)d_in[19];

  char* w = (char*)d_ws;
  unsigned short* XA   = (unsigned short*)(w);                 // 20,480,000 B
  unsigned short* XB   = (unsigned short*)(w + 20480000);      // 20,480,000 B
  unsigned short* OutA = (unsigned short*)(w + 40960000);      // 102,400,000 B
  unsigned short* OutB = (unsigned short*)(w + 143360000);     // 61,440,000 B
  unsigned short* WT_A = (unsigned short*)(w + 204800000);     // 655,360 B
  unsigned short* WT_B = (unsigned short*)(w + 205455360);     // 393,216 B
  unsigned short* WaT  = (unsigned short*)(w + 205848576);     // 262,144 B
  float* biasA = (float*)(w + 206110720);                      // 5,120 B
  float* biasB = (float*)(w + 206115840);                      // 3,072 B
  int* cnt  = (int*)(w + 206118912);                           // 3 x 160,000 B
  int* bkt  = (int*)(w + 206598912);                           // 3 x 10,240,000 B
  unsigned short* tA = (unsigned short*)(w + 237318912);       // 20,480,000 B
  unsigned short* tB = (unsigned short*)(w + 257798912);       // 20,480,000 B

  hipMemsetAsync(cnt, 0, 3 * NN * sizeof(int), stream);
  prep_all<<<16084, 256, 0, stream>>>(hA, hB, XA, XB,
                                      Wk, bk, Wq, bq, Wv, bv, Wa,
                                      rel_att, rel_msg, rel_pri,
                                      WT_A, WT_B, WaT, biasA, biasB,
                                      src0, dst0, src1, dst1, src2, dst2, cnt, bkt);
  gemm_kvq<<<10000, 256, 0, stream>>>(XA, XB, WT_A, WT_B, biasA, biasB, OutA, OutB);
  agg_all<<<20000, 256, 0, stream>>>(OutA, OutB, cnt, bkt, tA, tB);
  gemm_final2<<<dim3(1250, 2), 256, 0, stream>>>(tA, tB, XA, XB, WaT, ba, skip, (float*)d_out);
}